// Round 10
// baseline (1453.206 us; speedup 1.0000x reference)
//
#include <hip/hip_runtime.h>

static constexpr int DIM   = 256;
static constexpr int NCODE = 8192;
static constexpr int NROWS = 16384;

typedef __bf16 bf16x8 __attribute__((ext_vector_type(8)));
typedef float  f32x4  __attribute__((ext_vector_type(4)));

// ---------------------------------------------------------------------------
// top2 helpers (validated rounds 1-7)
// ---------------------------------------------------------------------------
__device__ __forceinline__ void top2_insert(float& v0, int& i0, float& v1, int& i1,
                                            float s, int si) {
    if (s < v0) { v1 = v0; i1 = i0; v0 = s; i0 = si; }
    else if (s < v1) { v1 = s; i1 = si; }
}
__device__ __forceinline__ void top2_merge(float& v0, int& i0, float& v1, int& i1,
                                           float b0, int bi0, float b1, int bi1) {
    if (b0 < v0) {
        if (b1 < v0) { v0 = b0; i0 = bi0; v1 = b1; i1 = bi1; }
        else         { v1 = v0; i1 = i0;  v0 = b0; i0 = bi0; }
    } else if (b0 < v1) { v1 = b0; i1 = bi0; }
}

// ---------------------------------------------------------------------------
// P0 fused prep (verbatim round 7)
// ---------------------------------------------------------------------------
__global__ __launch_bounds__(256) void prep_kernel(
    const float* __restrict__ x, const float* __restrict__ embed,
    ushort* __restrict__ xb, ushort* __restrict__ eb16, float* __restrict__ e2)
{
    __shared__ float tile[64][65];
    const int b = blockIdx.x;
    const int t = threadIdx.x;

    if (b < 2048) {                      // ---- cvt_x ----
        int i = b * 256 + t;
        const float4* xp = (const float4*)x + (size_t)i * 2;
        float4 a = xp[0], v = xp[1];
        bf16x8 o;
        o[0] = (__bf16)a.x; o[1] = (__bf16)a.y; o[2] = (__bf16)a.z; o[3] = (__bf16)a.w;
        o[4] = (__bf16)v.x; o[5] = (__bf16)v.y; o[6] = (__bf16)v.z; o[7] = (__bf16)v.w;
        ((bf16x8*)xb)[i] = o;
    } else if (b < 2560) {               // ---- cvt_e (transpose + bf16) ----
        const int eb = b - 2048;
        const int c00 = (eb & 127) * 64;
        const int k0  = (eb >> 7) * 64;
        const int tc  = t & 63, tr4 = t >> 6;
        #pragma unroll
        for (int i = 0; i < 16; ++i) {
            int r = i * 4 + tr4;
            tile[r][tc] = embed[(size_t)(k0 + r) * NCODE + c00 + tc];
        }
        __syncthreads();
        const int cl = t >> 2;
        const int kq = t & 3;
        float vals[16];
        #pragma unroll
        for (int j = 0; j < 16; ++j) vals[j] = tile[kq * 16 + j][cl];
        bf16x8 h0, h1;
        #pragma unroll
        for (int j = 0; j < 8; ++j) { h0[j] = (__bf16)vals[j]; h1[j] = (__bf16)vals[8 + j]; }
        ushort* d16 = eb16 + (size_t)(c00 + cl) * DIM + k0 + kq * 16;
        *(bf16x8*)d16 = h0;
        *(bf16x8*)(d16 + 8) = h1;
    } else {                             // ---- e2 (exact serial chain) ----
        int j = (b - 2560) * 256 + t;
        float s = 0.f;
        for (int k = 0; k < DIM; ++k) {
            float v = embed[(size_t)k * NCODE + j];
            s = __fadd_rn(s, __fmul_rn(v, v));
        }
        e2[j] = s;
    }
}

// ---------------------------------------------------------------------------
// K1 ABLATION PROBE. Same structure as round 7; template V selects variant:
//   V0 = full, launch_bounds(256,2)  (R7-identical; real scratch; runs LAST)
//   V7 = full, launch_bounds(256,1)  (register freedom; writes scratch,
//        values identical to V0 which overwrites afterwards anyway)
//   V1 = empty loop (prologue+skeleton only)
//   V3 = gather A-loads only, no MFMA
//   V4 = MFMA only, A-frags from LDS (no global loads in loop)
//   V2 = loads+MFMA, no top2 epilogue
// Sinks keep ablated values live (rule #17); dummy stores are racy-but-dead.
// ---------------------------------------------------------------------------
template<int V>
__global__ __launch_bounds__(256, (V == 7 ? 1 : 2)) void gemm_probe(
    const ushort* __restrict__ xb,   // [NROWS][256] bf16
    const ushort* __restrict__ eb,   // [NCODE][256] bf16 (embed^T)
    const float* __restrict__ e2g,   // [NCODE]
    uint2* __restrict__ outp)        // real scratch (V0,V7) or dummy (others)
{
    __shared__ ushort Bs[32768];     // 64 KB

    const int t       = threadIdx.x;
    const int cpair   = blockIdx.x >> 3;     // 0..63  (128 codes)
    const int rg      = blockIdx.x & 7;      // 0..7   (2048 rows)
    const int c0      = cpair * 128;
    const int rowbase = rg * 2048;

    const int wid = t >> 6, lane = t & 63;
    const int wr  = wid >> 1, wc = wid & 1;  // 2 x 2 wave grid
    const int lr  = lane & 15, g = lane >> 4;

    // ---- stage B once: linear global loads, swizzled LDS writes ----
    {
        const char* bb = (const char*)(eb + (size_t)c0 * DIM);
        uint4 breg[16];
        #pragma unroll
        for (int i = 0; i < 16; ++i)
            breg[i] = *(const uint4*)(bb + i * 4096 + t * 16);
        #pragma unroll
        for (int i = 0; i < 16; ++i) {
            int o = i * 4096 + t * 16;
            int code = o >> 9, kg = (o >> 4) & 31;
            *(uint4*)((char*)Bs + kg * 2048 + (((code + kg) & 127) << 4)) = breg[i];
        }
    }
    __syncthreads();                 // the ONLY barrier

    // ---- hoist B panel to registers: bq[cf][ks] ----
    bf16x8 bq[4][8];
    #pragma unroll
    for (int cf = 0; cf < 4; ++cf) {
        #pragma unroll
        for (int ks = 0; ks < 8; ++ks) {
            int codeL = wc * 64 + cf * 16 + lr;
            int kg    = ks * 4 + g;
            bq[cf][ks] = *(const bf16x8*)((char*)Bs + kg * 2048 +
                                          (((codeL + kg) & 127) << 4));
        }
    }

    uint4 usink = make_uint4(0u, 0u, 0u, 0u);
    f32x4 fsink = (f32x4){0.f, 0.f, 0.f, 0.f};

    if constexpr (V == 1 || V == 3) {    // keep the hoist live without MFMA
        #pragma unroll
        for (int cf = 0; cf < 4; ++cf)
            #pragma unroll
            for (int ks = 0; ks < 8; ++ks) {
                uint4 u = *(const uint4*)&bq[cf][ks];
                usink.x ^= u.x; usink.y ^= u.y; usink.z ^= u.z; usink.w ^= u.w;
            }
    }

    float e2v[4][4];
    #pragma unroll
    for (int cf = 0; cf < 4; ++cf)
        #pragma unroll
        for (int reg = 0; reg < 4; ++reg)
            e2v[cf][reg] = e2g[c0 + wc * 64 + cf * 16 + g * 4 + reg];

    const char* ab   = (const char*)xb;
    const int   ccol = cpair * 2 + wc;

    auto body = [&](int tt) {
        const int row0 = rowbase + tt * 64 + wr * 32;

        if constexpr (V == 1) {          // empty loop: dependent hash only
            usink.x = usink.x * 2654435761u + (unsigned)row0;
            return;
        }

        f32x4 acc[4][2];
        #pragma unroll
        for (int cf = 0; cf < 4; ++cf)
            #pragma unroll
            for (int rf = 0; rf < 2; ++rf) acc[cf][rf] = (f32x4){0.f, 0.f, 0.f, 0.f};

        #pragma unroll
        for (int half = 0; half < 2; ++half) {
            bf16x8 af[4][2];
            if constexpr (V != 4) {      // global A loads (baseline gather path)
                #pragma unroll
                for (int k4 = 0; k4 < 4; ++k4)
                    #pragma unroll
                    for (int rf = 0; rf < 2; ++rf)
                        af[k4][rf] = *(const bf16x8*)(ab +
                            (size_t)(row0 + rf * 16 + lr) * 512 +
                            (half * 4 + k4) * 64 + g * 16);
            } else {                     // LDS pseudo-A (no global loads)
                #pragma unroll
                for (int k4 = 0; k4 < 4; ++k4)
                    #pragma unroll
                    for (int rf = 0; rf < 2; ++rf) {
                        int kg = (half * 4 + k4) * 4 + g;
                        af[k4][rf] = *(const bf16x8*)((char*)Bs + kg * 2048 +
                            (((lr + rf * 16 + kg) & 127) << 4));
                    }
            }
            if constexpr (V == 3) {      // gather loads-only: xor-sink keeps af live
                #pragma unroll
                for (int k4 = 0; k4 < 4; ++k4)
                    #pragma unroll
                    for (int rf = 0; rf < 2; ++rf) {
                        uint4 u = *(const uint4*)&af[k4][rf];
                        usink.x ^= u.x; usink.y ^= u.y;
                        usink.z ^= u.z; usink.w ^= u.w;
                    }
            } else {
                #pragma unroll
                for (int k4 = 0; k4 < 4; ++k4)
                    #pragma unroll
                    for (int cf = 0; cf < 4; ++cf)
                        #pragma unroll
                        for (int rf = 0; rf < 2; ++rf)
                            acc[cf][rf] = __builtin_amdgcn_mfma_f32_16x16x32_bf16(
                                bq[cf][half * 4 + k4], af[k4][rf], acc[cf][rf], 0, 0, 0);
            }
        }

        if constexpr (V == 0 || V == 7) {   // full epilogue (validated R7)
            #pragma unroll
            for (int rf = 0; rf < 2; ++rf) {
                float v0 = __builtin_inff(), v1 = __builtin_inff();
                int   i0 = -1, i1 = -1;
                #pragma unroll
                for (int cf = 0; cf < 4; ++cf) {
                    #pragma unroll
                    for (int reg = 0; reg < 4; ++reg) {
                        float sv = __builtin_fmaf(-2.f, acc[cf][rf][reg], e2v[cf][reg]);
                        top2_insert(v0, i0, v1, i1, sv,
                                    c0 + wc * 64 + cf * 16 + g * 4 + reg);
                    }
                }
                #pragma unroll
                for (int m = 16; m <= 32; m <<= 1) {
                    float b0 = __shfl_xor(v0, m), b1 = __shfl_xor(v1, m);
                    int  bi0 = __shfl_xor(i0, m), bi1 = __shfl_xor(i1, m);
                    top2_merge(v0, i0, v1, i1, b0, bi0, b1, bi1);
                }
                if (g == 0) {
                    float delta = v1 - v0;
                    unsigned dq = (unsigned)min(63, (int)(delta * 32.f));
                    unsigned w2 = (unsigned)i0 | ((unsigned)i1 << 13) | (dq << 26);
                    outp[(size_t)ccol * NROWS + row0 + rf * 16 + lr] =
                        make_uint2(__float_as_uint(v0), w2);
                }
            }
        } else if constexpr (V == 2 || V == 4) {  // acc sink, no top2
            #pragma unroll
            for (int cf = 0; cf < 4; ++cf)
                #pragma unroll
                for (int rf = 0; rf < 2; ++rf) fsink += acc[cf][rf];
        }
    };

    for (int tt = 0; tt < 32; ++tt) body(tt);

    if constexpr (V != 0 && V != 7) {    // dummy sink store (racy, never read)
        int gid = blockIdx.x * 256 + t;
        outp[gid & 65535] = make_uint2(usink.x ^ usink.z, usink.y ^ usink.w);
        outp[(gid + 77) & 65535] =
            make_uint2(__float_as_uint(fsink[0] + fsink[2]),
                       __float_as_uint(fsink[1] + fsink[3]));
    }
}

// ---------------------------------------------------------------------------
// K2 fused finalize (verbatim round 7 — validated)
// ---------------------------------------------------------------------------
__global__ __launch_bounds__(256) void finalize_kernel(
    const uint2* __restrict__ scratch, const float* __restrict__ x,
    const float* __restrict__ embed, const float* __restrict__ e2g,
    float* __restrict__ quant, float* __restrict__ diff, float* __restrict__ ind)
{
    __shared__ float    wmin[4][64];
    __shared__ float    thr[64];
    __shared__ unsigned cnt[64];
    __shared__ unsigned cand[64][12];
    __shared__ unsigned bestIdx[64];
    __shared__ float    partial[4];

    const int t  = threadIdx.x;
    const int w  = t >> 6, l = t & 63;
    const int R0 = blockIdx.x * 64;

    if (t < 64) cnt[t] = 0;

    float m = __builtin_inff();
    #pragma unroll 4
    for (int i = 0; i < 32; ++i) {
        uint2 e = scratch[(size_t)(w * 32 + i) * NROWS + R0 + l];
        m = fminf(m, __uint_as_float(e.x));
    }
    wmin[w][l] = m;
    __syncthreads();
    if (t < 64)
        thr[t] = fminf(fminf(wmin[0][t], wmin[1][t]),
                       fminf(wmin[2][t], wmin[3][t])) + 1.0f;
    __syncthreads();

    const float th = thr[l];
    for (int i = 0; i < 32; ++i) {
        uint2 e = scratch[(size_t)(w * 32 + i) * NROWS + R0 + l];
        float v0 = __uint_as_float(e.x);
        if (v0 <= th) {
            unsigned s = atomicAdd(&cnt[l], 1u);
            if (s < 12) cand[l][s] = e.y & 8191u;
        }
        float v1lo = v0 + (float)((e.y >> 26) & 63u) * 0.03125f;
        if (v1lo <= th) {
            unsigned s = atomicAdd(&cnt[l], 1u);
            if (s < 12) cand[l][s] = (e.y >> 13) & 8191u;
        }
    }
    __syncthreads();

    const int rl = l >> 2, slot = l & 3;
    const int rrow = R0 + w * 16 + rl;
    const int cn = min((int)cnt[w * 16 + rl], 12);
    float best = __builtin_inff();
    unsigned bidx = 0xFFFFFFFFu;
    for (int s = slot; s < cn; s += 4) {
        unsigned idx = cand[w * 16 + rl][s];
        const float* xr = x + (size_t)rrow * DIM;
        float f2 = 0.f, dot = 0.f;
        for (int k = 0; k < DIM; ++k) {
            float xv = xr[k];
            f2  = __fadd_rn(f2, __fmul_rn(xv, xv));
            dot = __builtin_fmaf(xv, embed[(size_t)k * NCODE + idx], dot);
        }
        float d = __fadd_rn(__builtin_fmaf(-2.f, dot, f2), e2g[idx]);
        if (d < best || (d == best && idx < bidx)) { best = d; bidx = idx; }
    }
    #pragma unroll
    for (int mm = 1; mm < 4; mm <<= 1) {
        float    od = __shfl_xor(best, mm);
        unsigned oi = (unsigned)__shfl_xor((int)bidx, mm);
        if (od < best || (od == best && oi < bidx)) { best = od; bidx = oi; }
    }
    if (slot == 0) bestIdx[w * 16 + rl] = bidx;
    __syncthreads();

    float accv = 0.f;
    for (int r = 0; r < 64; ++r) {
        const int row2 = R0 + r;
        const unsigned idx = bestIdx[r];
        float xv = x[(size_t)row2 * DIM + t];
        float q  = embed[(size_t)t * NCODE + idx];
        float dq = __fsub_rn(q, xv);
        quant[(size_t)row2 * DIM + t] = __fadd_rn(xv, dq);
        accv += __fmul_rn(dq, dq);
    }
    #pragma unroll
    for (int off = 32; off >= 1; off >>= 1) accv += __shfl_down(accv, off);
    if (l == 0) partial[w] = accv;
    __syncthreads();
    if (t == 0) {
        float s = (partial[0] + partial[1]) + (partial[2] + partial[3]);
        atomicAdd(diff, s * (1.25f / 4194304.f));
    }
    if (t < 64) ind[R0 + t] = (float)bestIdx[t];
}

// ---------------------------------------------------------------------------
extern "C" void kernel_launch(void* const* d_in, const int* in_sizes, int n_in,
                              void* d_out, int out_size, void* d_ws, size_t ws_size,
                              hipStream_t stream)
{
    const float* x     = (const float*)d_in[0];   // [16384,256]
    const float* embed = (const float*)d_in[1];   // [256,8192]

    float* out   = (float*)d_out;
    float* quant = out;
    float* diff  = out + 4194304;
    float* ind   = out + 4194305;

    // xb (bf16 x, 8 MB) overlays the quantize region (prep->gemm->finalize)
    ushort* xb = (ushort*)quant;

    // workspace (21.5 MB)
    char* w = (char*)d_ws;
    ushort* eb16    = (ushort*)(w);               //  4 MB
    uint2*  scratch = (uint2*) (w + 4194304);     // 16 MB  [128][16384]
    float*  e2      = (float*) (w + 20971520);    // 32 KB
    uint2*  dummy   = (uint2*) (w + 21004288);    // 512 KB ablation sink

    prep_kernel<<<2592, 256, 0, stream>>>(x, embed, xb, eb16, e2);

    // ---- ablation probes ----
    gemm_probe<1><<<512, 256, 0, stream>>>(xb, eb16, e2, dummy);   // empty loop
    gemm_probe<3><<<512, 256, 0, stream>>>(xb, eb16, e2, dummy);   // gather loads only
    gemm_probe<4><<<512, 256, 0, stream>>>(xb, eb16, e2, dummy);   // MFMA only (LDS A)
    gemm_probe<2><<<512, 256, 0, stream>>>(xb, eb16, e2, dummy);   // loads+MFMA
    gemm_probe<7><<<512, 256, 0, stream>>>(xb, eb16, e2, scratch); // full, lb(256,1)
    // ---- real result (identical to round-7 kernel) ----
    gemm_probe<0><<<512, 256, 0, stream>>>(xb, eb16, e2, scratch);

    hipMemsetAsync(diff, 0, sizeof(float), stream);
    finalize_kernel<<<256, 256, 0, stream>>>(scratch, x, embed, e2, quant, diff, ind);
}